// Round 8
// baseline (474.006 us; speedup 1.0000x reference)
//
#include <hip/hip_runtime.h>
#include <math.h>
#include <float.h>

#define NROWS 131072
#define SDIM 64
#define HDIM 128
#define KCODES 512
#define ADIM 8
#define LSTR 66   // LDS row stride: banks (66*t + l)%32 -> 2 lanes/bank (free)

// ===========================================================================
// prep: eT[j][c] = emb[c][j]  (256 KB) so per-j code-blocks are contiguous
// wave-uniform runs -> s_load_dwordx16 on the scalar pipe.
// ===========================================================================
__global__ void prep_e_kernel(const float* __restrict__ emb, float* __restrict__ eT) {
    int g = blockIdx.x * 256 + threadIdx.x;        // 0..16383
    int c = g >> 5, j4 = g & 31;
    float4 v = ((const float4*)emb)[(size_t)c * 32 + j4];
    eT[(size_t)(4 * j4 + 0) * KCODES + c] = v.x;
    eT[(size_t)(4 * j4 + 1) * KCODES + c] = v.y;
    eT[(size_t)(4 * j4 + 2) * KCODES + c] = v.z;
    eT[(size_t)(4 * j4 + 3) * KCODES + c] = v.w;
}

// ee[k] = sum_j emb[k][j]^2 — exact FP chain from rounds 1-7 (absmax 0.0)
__global__ void ee_kernel(const float* __restrict__ emb, float* __restrict__ ee) {
    int k = blockIdx.x * blockDim.x + threadIdx.x;
    if (k >= KCODES) return;
    const float* e = emb + k * HDIM;
    float a0 = 0.f, a1 = 0.f, a2 = 0.f, a3 = 0.f;
#pragma unroll
    for (int j = 0; j < HDIM; j += 4) {
        a0 = fmaf(e[j + 0], e[j + 0], a0);
        a1 = fmaf(e[j + 1], e[j + 1], a1);
        a2 = fmaf(e[j + 2], e[j + 2], a2);
        a3 = fmaf(e[j + 3], e[j + 3], a3);
    }
    ee[k] = (a0 + a1) + (a2 + a3);
}

// ===========================================================================
// Megafused: MLP + VQ + heads in one kernel. Block = 256 thr (4 waves) x
// 64 rows; lane l owns row brow+l, wave wu owns a 32-col slice (MLP) and a
// 128-code slice (VQ). LDS = inT 16.9K + xT 33.8K (x1T then x2T in place;
// layer-2 accumulates in registers so overwrite-after-barrier is safe) +
// red 2K = 52.7 KB -> 3 blocks/CU = 3 waves/SIMD (vs round-7's 2).
// Streamed matrices (W1/Wh/eT/ee) via readfirstlane-uniform s_load (SGPRs,
// scalar pipe). FP chains identical to rounds 1-7 (absmax 0.0).
// ===========================================================================
__global__ __launch_bounds__(256, 3) void megafused_kernel(
    const float* __restrict__ in,
    const float* __restrict__ W1, const float* __restrict__ b1,
    const float* __restrict__ Wh, const float* __restrict__ bh,
    const float* __restrict__ emb,
    const float* __restrict__ eT, const float* __restrict__ eew,
    const float* __restrict__ Wa, const float* __restrict__ ba,
    const float* __restrict__ Wv, const float* __restrict__ bv,
    float* __restrict__ out)
{
    __shared__ float inT[SDIM * LSTR];            // 16.9 KB
    __shared__ float xT[HDIM * LSTR];             // 33.8 KB: x1^T, then x2^T
    __shared__ float redb[4][64];
    __shared__ int   redi[4][64];
    const int tid = threadIdx.x;
    const int wu = __builtin_amdgcn_readfirstlane(tid >> 6);  // uniform wave id
    const int l = tid & 63;
    const int brow = blockIdx.x * 64;
    const int c0 = wu * 32;                       // uniform col/code base

    // --- stage inT[s][r] = in[brow+r][s] (coalesced b128 global reads) ---
    {
        const float4* src = (const float4*)(in + (size_t)brow * SDIM);
#pragma unroll
        for (int u = 0; u < 4; ++u) {
            int idx = tid + 256 * u;              // 0..1023 b128 units
            int r = idx >> 4, s4 = idx & 15;
            float4 v = src[idx];
            inT[(4 * s4 + 0) * LSTR + r] = v.x;
            inT[(4 * s4 + 1) * LSTR + r] = v.y;
            inT[(4 * s4 + 2) * LSTR + r] = v.z;
            inT[(4 * s4 + 3) * LSTR + r] = v.w;
        }
    }
    __syncthreads();

    // --- layer1: x1[t], t in [c0,c0+32), row l; s ascending (exact) ---
    {
        float acc[32];
#pragma unroll
        for (int cc = 0; cc < 32; ++cc) acc[cc] = b1[c0 + cc];
#pragma unroll 4
        for (int s = 0; s < SDIM; ++s) {
            float xa = inT[s * LSTR + l];
            const float* wr = W1 + s * HDIM + c0;     // uniform -> s_load x16
#pragma unroll
            for (int cc = 0; cc < 32; ++cc) acc[cc] = fmaf(xa, wr[cc], acc[cc]);
        }
#pragma unroll
        for (int cc = 0; cc < 32; ++cc) xT[(c0 + cc) * LSTR + l] = fmaxf(acc[cc], 0.f);
    }
    __syncthreads();

    // --- layer2: x2 cols [c0,c0+32) in REGISTERS; t ascending (exact) ---
    float acc2[32];
#pragma unroll
    for (int cc = 0; cc < 32; ++cc) acc2[cc] = bh[c0 + cc];
#pragma unroll 4
    for (int t = 0; t < HDIM; ++t) {
        float xa = xT[t * LSTR + l];
        const float* wr = Wh + t * HDIM + c0;         // uniform -> s_load x16
#pragma unroll
        for (int cc = 0; cc < 32; ++cc) acc2[cc] = fmaf(xa, wr[cc], acc2[cc]);
    }
    __syncthreads();                              // all x1T reads complete
#pragma unroll
    for (int cc = 0; cc < 32; ++cc) xT[(c0 + cc) * LSTR + l] = fmaxf(acc2[cc], 0.f);
    __syncthreads();                              // xT now holds x2^T

    // --- vv = ||x||^2: 4 chains by j%4, j ascending (exact) ---
    float v0 = 0.f, v1 = 0.f, v2 = 0.f, v3 = 0.f;
#pragma unroll 4
    for (int j4 = 0; j4 < 32; ++j4) {
        int j = 4 * j4;
        float a0 = xT[(j + 0) * LSTR + l], a1 = xT[(j + 1) * LSTR + l];
        float a2 = xT[(j + 2) * LSTR + l], a3 = xT[(j + 3) * LSTR + l];
        v0 = fmaf(a0, a0, v0); v1 = fmaf(a1, a1, v1);
        v2 = fmaf(a2, a2, v2); v3 = fmaf(a3, a3, v3);
    }
    const float vv = (v0 + v1) + (v2 + v3);

    // --- VQ scoring: wave wu owns codes [wu*128, wu*128+128), 4 groups ---
    float best = FLT_MAX;
    int bi = 0;
    for (int g = 0; g < 4; ++g) {
        const int k0 = wu * 128 + g * 32;             // uniform
        float d[32];
#pragma unroll
        for (int cc = 0; cc < 32; ++cc) d[cc] = 0.f;
#pragma unroll 2
        for (int j = 0; j < HDIM; ++j) {              // j ascending: exact
            float xa = xT[j * LSTR + l];
            const float* er = eT + (size_t)j * KCODES + k0;   // uniform -> s_load x16
#pragma unroll
            for (int cc = 0; cc < 32; ++cc) d[cc] = fmaf(xa, er[cc], d[cc]);
        }
        const float* eg = eew + k0;                   // uniform -> s_load
#pragma unroll
        for (int cc = 0; cc < 32; ++cc) {
            float dd = (vv - 2.f * d[cc]) + eg[cc];
            if (dd < best) { best = dd; bi = k0 + cc; }   // strict <: first wins
        }
    }

    // --- cross-wave argmin (wave blocks ascending = code order, exact) ---
    redb[wu][l] = best;  redi[wu][l] = bi;
    __syncthreads();

    if (tid < 64) {
        float bb = redb[0][tid];
        int bix = redi[0][tid];
#pragma unroll
        for (int q = 1; q < 4; ++q) {
            float b = redb[q][tid];
            if (b < bb) { bb = b; bix = redi[q][tid]; }
        }

        // --- heads: quantize = emb[bix]; exact FP order of rounds 1-7 ---
        const int row = brow + tid;
        float lg[ADIM];
#pragma unroll
        for (int a = 0; a < ADIM; ++a) lg[a] = ba[a];
        float val = bv[0];

        const float4* q4 = (const float4*)(emb + (size_t)bix * HDIM);
#pragma unroll
        for (int j4 = 0; j4 < HDIM / 4; ++j4) {
            float4 q = q4[j4];
            const int j = 4 * j4;
#pragma unroll
            for (int a = 0; a < ADIM; ++a) {
                float t = lg[a];
                t = fmaf(q.x, Wa[(j + 0) * ADIM + a], t);
                t = fmaf(q.y, Wa[(j + 1) * ADIM + a], t);
                t = fmaf(q.z, Wa[(j + 2) * ADIM + a], t);
                t = fmaf(q.w, Wa[(j + 3) * ADIM + a], t);
                lg[a] = t;
            }
            val = fmaf(q.x, Wv[j + 0], val);
            val = fmaf(q.y, Wv[j + 1], val);
            val = fmaf(q.z, Wv[j + 2], val);
            val = fmaf(q.w, Wv[j + 3], val);
        }

        float m = lg[0];
#pragma unroll
        for (int a = 1; a < ADIM; ++a) m = fmaxf(m, lg[a]);
        float p[ADIM];
        float s = 0.f;
#pragma unroll
        for (int a = 0; a < ADIM; ++a) { p[a] = __expf(lg[a] - m); s += p[a]; }
        const float inv = 1.f / s;

        float4* outp = (float4*)(out + (size_t)row * ADIM);
        outp[0] = make_float4(p[0] * inv, p[1] * inv, p[2] * inv, p[3] * inv);
        outp[1] = make_float4(p[4] * inv, p[5] * inv, p[6] * inv, p[7] * inv);
        out[(size_t)NROWS * ADIM + row] = val;
    }
}

// ===========================================================================
// Fallback (only if ws < 258 KB; never expected): round-4 global-feed path.
// ===========================================================================
#define R16(M) M(0) M(1) M(2) M(3) M(4) M(5) M(6) M(7) \
               M(8) M(9) M(10) M(11) M(12) M(13) M(14) M(15)
#define R32(M) R16(M) M(16) M(17) M(18) M(19) M(20) M(21) M(22) M(23) \
               M(24) M(25) M(26) M(27) M(28) M(29) M(30) M(31)
#define PIN4(v) asm volatile("" : "+v"(v.x), "+v"(v.y), "+v"(v.z), "+v"(v.w));

__global__ __launch_bounds__(256, 2) void fused_global_kernel(
    const float* __restrict__ in,
    const float* __restrict__ W1, const float* __restrict__ b1,
    const float* __restrict__ Wh, const float* __restrict__ bh,
    const float* __restrict__ emb,
    const float* __restrict__ Wa, const float* __restrict__ ba,
    const float* __restrict__ Wv, const float* __restrict__ bv,
    float* __restrict__ out)
{
    __shared__ float ee_s[KCODES];
    const int tid = threadIdx.x;
    const int row = blockIdx.x * 256 + tid;

#pragma unroll
    for (int kk = 0; kk < 2; ++kk) {
        int k = tid + 256 * kk;
        const float* e = emb + k * HDIM;
        float a0 = 0.f, a1 = 0.f, a2 = 0.f, a3 = 0.f;
#pragma unroll
        for (int j = 0; j < HDIM; j += 4) {
            a0 = fmaf(e[j + 0], e[j + 0], a0);
            a1 = fmaf(e[j + 1], e[j + 1], a1);
            a2 = fmaf(e[j + 2], e[j + 2], a2);
            a3 = fmaf(e[j + 3], e[j + 3], a3);
        }
        ee_s[k] = (a0 + a1) + (a2 + a3);
    }
    __syncthreads();

    const float4* inr4 = (const float4*)(in + (size_t)row * SDIM);
#define DECLI(n) float4 i##n = inr4[n]; PIN4(i##n)
    R16(DECLI)
#define DECLX(m) float4 x##m = make_float4(bh[4*(m)+0], bh[4*(m)+1], bh[4*(m)+2], bh[4*(m)+3]);
    R32(DECLX)

#define L1N(n) xt = fmaf(i##n.x, wc[(4*(n)+0)*HDIM], xt); xt = fmaf(i##n.y, wc[(4*(n)+1)*HDIM], xt); \
               xt = fmaf(i##n.z, wc[(4*(n)+2)*HDIM], xt); xt = fmaf(i##n.w, wc[(4*(n)+3)*HDIM], xt);
#define L2(m)  x##m.x = fmaf(xt, whr[4*(m)+0], x##m.x); x##m.y = fmaf(xt, whr[4*(m)+1], x##m.y); \
               x##m.z = fmaf(xt, whr[4*(m)+2], x##m.z); x##m.w = fmaf(xt, whr[4*(m)+3], x##m.w);
    for (int t = 0; t < HDIM; ++t) {
        float xt = b1[t];
        const float* wc = W1 + t;
        R16(L1N)
        xt = fmaxf(xt, 0.f);
        const float* whr = Wh + t * HDIM;
        R32(L2)
    }
#define RELUX(m) x##m.x = fmaxf(x##m.x, 0.f); x##m.y = fmaxf(x##m.y, 0.f); \
                 x##m.z = fmaxf(x##m.z, 0.f); x##m.w = fmaxf(x##m.w, 0.f); PIN4(x##m)
    R32(RELUX)

    float v0 = 0.f, v1 = 0.f, v2 = 0.f, v3 = 0.f;
#define VV(m) v0 = fmaf(x##m.x, x##m.x, v0); v1 = fmaf(x##m.y, x##m.y, v1); \
              v2 = fmaf(x##m.z, x##m.z, v2); v3 = fmaf(x##m.w, x##m.w, v3);
    R32(VV)
    const float vv = (v0 + v1) + (v2 + v3);

    float best = FLT_MAX;
    int bi = 0;
#define SC(m) \
    d0 = fmaf(x##m.x, eb[0*HDIM+4*(m)+0], d0); d0 = fmaf(x##m.y, eb[0*HDIM+4*(m)+1], d0); \
    d0 = fmaf(x##m.z, eb[0*HDIM+4*(m)+2], d0); d0 = fmaf(x##m.w, eb[0*HDIM+4*(m)+3], d0); \
    d1 = fmaf(x##m.x, eb[1*HDIM+4*(m)+0], d1); d1 = fmaf(x##m.y, eb[1*HDIM+4*(m)+1], d1); \
    d1 = fmaf(x##m.z, eb[1*HDIM+4*(m)+2], d1); d1 = fmaf(x##m.w, eb[1*HDIM+4*(m)+3], d1); \
    d2 = fmaf(x##m.x, eb[2*HDIM+4*(m)+0], d2); d2 = fmaf(x##m.y, eb[2*HDIM+4*(m)+1], d2); \
    d2 = fmaf(x##m.z, eb[2*HDIM+4*(m)+2], d2); d2 = fmaf(x##m.w, eb[2*HDIM+4*(m)+3], d2); \
    d3 = fmaf(x##m.x, eb[3*HDIM+4*(m)+0], d3); d3 = fmaf(x##m.y, eb[3*HDIM+4*(m)+1], d3); \
    d3 = fmaf(x##m.z, eb[3*HDIM+4*(m)+2], d3); d3 = fmaf(x##m.w, eb[3*HDIM+4*(m)+3], d3); \
    d4 = fmaf(x##m.x, eb[4*HDIM+4*(m)+0], d4); d4 = fmaf(x##m.y, eb[4*HDIM+4*(m)+1], d4); \
    d4 = fmaf(x##m.z, eb[4*HDIM+4*(m)+2], d4); d4 = fmaf(x##m.w, eb[4*HDIM+4*(m)+3], d4); \
    d5 = fmaf(x##m.x, eb[5*HDIM+4*(m)+0], d5); d5 = fmaf(x##m.y, eb[5*HDIM+4*(m)+1], d5); \
    d5 = fmaf(x##m.z, eb[5*HDIM+4*(m)+2], d5); d5 = fmaf(x##m.w, eb[5*HDIM+4*(m)+3], d5); \
    d6 = fmaf(x##m.x, eb[6*HDIM+4*(m)+0], d6); d6 = fmaf(x##m.y, eb[6*HDIM+4*(m)+1], d6); \
    d6 = fmaf(x##m.z, eb[6*HDIM+4*(m)+2], d6); d6 = fmaf(x##m.w, eb[6*HDIM+4*(m)+3], d6); \
    d7 = fmaf(x##m.x, eb[7*HDIM+4*(m)+0], d7); d7 = fmaf(x##m.y, eb[7*HDIM+4*(m)+1], d7); \
    d7 = fmaf(x##m.z, eb[7*HDIM+4*(m)+2], d7); d7 = fmaf(x##m.w, eb[7*HDIM+4*(m)+3], d7);
    for (int k0 = 0; k0 < KCODES; k0 += 8) {
        const float* eb = emb + (size_t)k0 * HDIM;
        float d0 = 0.f, d1 = 0.f, d2 = 0.f, d3 = 0.f;
        float d4 = 0.f, d5 = 0.f, d6 = 0.f, d7 = 0.f;
        R32(SC)
        float dd;
        dd = (vv - 2.f * d0) + ee_s[k0 + 0]; if (dd < best) { best = dd; bi = k0 + 0; }
        dd = (vv - 2.f * d1) + ee_s[k0 + 1]; if (dd < best) { best = dd; bi = k0 + 1; }
        dd = (vv - 2.f * d2) + ee_s[k0 + 2]; if (dd < best) { best = dd; bi = k0 + 2; }
        dd = (vv - 2.f * d3) + ee_s[k0 + 3]; if (dd < best) { best = dd; bi = k0 + 3; }
        dd = (vv - 2.f * d4) + ee_s[k0 + 4]; if (dd < best) { best = dd; bi = k0 + 4; }
        dd = (vv - 2.f * d5) + ee_s[k0 + 5]; if (dd < best) { best = dd; bi = k0 + 5; }
        dd = (vv - 2.f * d6) + ee_s[k0 + 6]; if (dd < best) { best = dd; bi = k0 + 6; }
        dd = (vv - 2.f * d7) + ee_s[k0 + 7]; if (dd < best) { best = dd; bi = k0 + 7; }
    }

    float lg[ADIM];
#pragma unroll
    for (int a = 0; a < ADIM; ++a) lg[a] = ba[a];
    float val = bv[0];
    const float4* q4 = (const float4*)(emb + (size_t)bi * HDIM);
#pragma unroll
    for (int j4 = 0; j4 < HDIM / 4; ++j4) {
        float4 q = q4[j4];
        const int j = 4 * j4;
#pragma unroll
        for (int a = 0; a < ADIM; ++a) {
            float t = lg[a];
            t = fmaf(q.x, Wa[(j + 0) * ADIM + a], t);
            t = fmaf(q.y, Wa[(j + 1) * ADIM + a], t);
            t = fmaf(q.z, Wa[(j + 2) * ADIM + a], t);
            t = fmaf(q.w, Wa[(j + 3) * ADIM + a], t);
            lg[a] = t;
        }
        val = fmaf(q.x, Wv[j + 0], val);
        val = fmaf(q.y, Wv[j + 1], val);
        val = fmaf(q.z, Wv[j + 2], val);
        val = fmaf(q.w, Wv[j + 3], val);
    }
    float m = lg[0];
#pragma unroll
    for (int a = 1; a < ADIM; ++a) m = fmaxf(m, lg[a]);
    float p[ADIM];
    float s = 0.f;
#pragma unroll
    for (int a = 0; a < ADIM; ++a) { p[a] = __expf(lg[a] - m); s += p[a]; }
    const float inv = 1.f / s;
    float4* outp = (float4*)(out + (size_t)row * ADIM);
    outp[0] = make_float4(p[0] * inv, p[1] * inv, p[2] * inv, p[3] * inv);
    outp[1] = make_float4(p[4] * inv, p[5] * inv, p[6] * inv, p[7] * inv);
    out[(size_t)NROWS * ADIM + row] = val;
}

// ===========================================================================
extern "C" void kernel_launch(void* const* d_in, const int* in_sizes, int n_in,
                              void* d_out, int out_size, void* d_ws, size_t ws_size,
                              hipStream_t stream) {
    const float* in  = (const float*)d_in[0];
    const float* W1  = (const float*)d_in[1];
    const float* b1  = (const float*)d_in[2];
    const float* Wh  = (const float*)d_in[3];
    const float* bh  = (const float*)d_in[4];
    const float* emb = (const float*)d_in[5];
    const float* Wa  = (const float*)d_in[6];
    const float* ba  = (const float*)d_in[7];
    const float* Wv  = (const float*)d_in[8];
    const float* bv  = (const float*)d_in[9];
    float* out = (float*)d_out;

    const size_t eT_bytes = (size_t)KCODES * HDIM * sizeof(float);   // 256 KB
    const size_t ee_bytes = KCODES * sizeof(float);                  // 2 KB

    if (ws_size >= eT_bytes + ee_bytes) {
        float* eTp = (float*)d_ws;
        float* eew = eTp + (size_t)KCODES * HDIM;
        prep_e_kernel<<<64, 256, 0, stream>>>(emb, eTp);
        ee_kernel<<<2, 256, 0, stream>>>(emb, eew);
        megafused_kernel<<<NROWS / 64, 256, 0, stream>>>(in, W1, b1, Wh, bh, emb,
                                                         eTp, eew, Wa, ba, Wv, bv, out);
    } else {
        fused_global_kernel<<<NROWS / 256, 256, 0, stream>>>(in, W1, b1, Wh, bh, emb,
                                                             Wa, ba, Wv, bv, out);
    }
}

// Round 9
// 386.740 us; speedup vs baseline: 1.2256x; 1.2256x over previous
//
#include <hip/hip_runtime.h>
#include <math.h>
#include <float.h>

#define NROWS 131072
#define SDIM 64
#define HDIM 128
#define KCODES 512
#define ADIM 8

#define vvA_q(q) ((q) == 0 ? vvA.x : (q) == 1 ? vvA.y : (q) == 2 ? vvA.z : vvA.w)
#define vvB_q(q) ((q) == 0 ? vvB.x : (q) == 1 ? vvB.y : (q) == 2 ? vvB.z : vvB.w)

// ===========================================================================
// prep: eT[j][c] = emb[c][j]  (256 KB), j-major so VQ staging reads are
// coalesced rows of codes.
// ===========================================================================
__global__ void prep_e_kernel(const float* __restrict__ emb, float* __restrict__ eT) {
    int g = blockIdx.x * 256 + threadIdx.x;        // 0..16383
    int c = g >> 5, j4 = g & 31;
    float4 v = ((const float4*)emb)[(size_t)c * 32 + j4];
    eT[(size_t)(4 * j4 + 0) * KCODES + c] = v.x;
    eT[(size_t)(4 * j4 + 1) * KCODES + c] = v.y;
    eT[(size_t)(4 * j4 + 2) * KCODES + c] = v.z;
    eT[(size_t)(4 * j4 + 3) * KCODES + c] = v.w;
}

// ee[k] = sum_j emb[k][j]^2 — exact FP chain from rounds 1-8 (absmax 0.0)
__global__ void ee_kernel(const float* __restrict__ emb, float* __restrict__ ee) {
    int k = blockIdx.x * blockDim.x + threadIdx.x;
    if (k >= KCODES) return;
    const float* e = emb + k * HDIM;
    float a0 = 0.f, a1 = 0.f, a2 = 0.f, a3 = 0.f;
#pragma unroll
    for (int j = 0; j < HDIM; j += 4) {
        a0 = fmaf(e[j + 0], e[j + 0], a0);
        a1 = fmaf(e[j + 1], e[j + 1], a1);
        a2 = fmaf(e[j + 2], e[j + 2], a2);
        a3 = fmaf(e[j + 3], e[j + 3], a3);
    }
    ee[k] = (a0 + a1) + (a2 + a3);
}

// ===========================================================================
// MLP (round-7 structure): block = 256 thr x 128 rows; lane l owns rows l,
// l+64; wave wu owns cols [wu*32,+32). Weights via uniform s_load. Chains
// exact (x1 s-asc, x2 t-asc). Stores x2^T + vvs[row] (vv order is argmin-
// invariant: uniform per-row shift -> outputs stay bit-exact).
// ===========================================================================
__global__ __launch_bounds__(256, 2) void mlp_kernel(
    const float* __restrict__ in,
    const float* __restrict__ W1, const float* __restrict__ b1,
    const float* __restrict__ Wh, const float* __restrict__ bh,
    float* __restrict__ x2t, float* __restrict__ vvs, int rstride)
{
    __shared__ float buf[16384];                  // 64 KB
    const int tid = threadIdx.x;
    const int wu = __builtin_amdgcn_readfirstlane(tid >> 6);
    const int l = tid & 63;
    const int brow = blockIdx.x * 128;
    const int c0 = wu * 32;

    {
        const float4* src = (const float4*)(in + (size_t)brow * SDIM);
#pragma unroll
        for (int u = 0; u < 8; ++u) {
            int idx = tid + 256 * u;
            int r = idx >> 4, s4 = idx & 15;
            float4 v = src[idx];
            buf[(4 * s4 + 0) * 129 + r] = v.x;
            buf[(4 * s4 + 1) * 129 + r] = v.y;
            buf[(4 * s4 + 2) * 129 + r] = v.z;
            buf[(4 * s4 + 3) * 129 + r] = v.w;
        }
    }
    __syncthreads();

    float acc0[32], acc1[32];
#pragma unroll
    for (int cc = 0; cc < 32; ++cc) { acc0[cc] = b1[c0 + cc]; acc1[cc] = b1[c0 + cc]; }
#pragma unroll 4
    for (int s = 0; s < SDIM; ++s) {              // s ascending: exact chain
        float xa = buf[s * 129 + l];
        float xb = buf[s * 129 + l + 64];
        const float* wr = W1 + s * HDIM + c0;     // uniform -> s_load x16
#pragma unroll
        for (int cc = 0; cc < 32; ++cc) {
            acc0[cc] = fmaf(xa, wr[cc], acc0[cc]);
            acc1[cc] = fmaf(xb, wr[cc], acc1[cc]);
        }
    }
    __syncthreads();
#pragma unroll
    for (int cc = 0; cc < 32; ++cc) {
        buf[(c0 + cc) * 128 + l]      = fmaxf(acc0[cc], 0.f);
        buf[(c0 + cc) * 128 + l + 64] = fmaxf(acc1[cc], 0.f);
    }
    __syncthreads();

#pragma unroll
    for (int cc = 0; cc < 32; ++cc) { acc0[cc] = bh[c0 + cc]; acc1[cc] = bh[c0 + cc]; }
#pragma unroll 4
    for (int t = 0; t < HDIM; ++t) {              // t ascending: exact chain
        float xa = buf[t * 128 + l];
        float xb = buf[t * 128 + l + 64];
        const float* wr = Wh + t * HDIM + c0;     // uniform -> s_load x16
#pragma unroll
        for (int cc = 0; cc < 32; ++cc) {
            acc0[cc] = fmaf(xa, wr[cc], acc0[cc]);
            acc1[cc] = fmaf(xb, wr[cc], acc1[cc]);
        }
    }
    float pa = 0.f, pb = 0.f;
#pragma unroll
    for (int cc = 0; cc < 32; ++cc) {
        float a = fmaxf(acc0[cc], 0.f);
        float b = fmaxf(acc1[cc], 0.f);
        x2t[(size_t)(c0 + cc) * rstride + brow + l]      = a;
        x2t[(size_t)(c0 + cc) * rstride + brow + l + 64] = b;
        pa = fmaf(a, a, pa);
        pb = fmaf(b, b, pb);
    }
    __syncthreads();                              // x1T reads done; reuse buf
    buf[wu * 128 + l]      = pa;
    buf[wu * 128 + l + 64] = pb;
    __syncthreads();
    if (tid < 128) {
        float vv = ((buf[tid] + buf[128 + tid]) + buf[256 + tid]) + buf[384 + tid];
        vvs[brow + tid] = vv;
    }
}

// ===========================================================================
// VQ: register-blocked SGEMM. Block = 128 rows x 512 codes (4 panels),
// 256 thr; thread tile 8 rows x 8 codes. Per k-step: 4 conflict-free
// ds_read_b128 -> 64 FMA (LDS/VALU balanced at 100%). k-chunks of 32.
// Dot chain k 0..127 ascending single acc (exact); first-min semantics
// via strict < (cb,ci asc) + index tie-break. Heads inline (exact chain).
// LDS 35 KB -> 4 blocks/CU = 4 waves/SIMD.
// ===========================================================================
__global__ __launch_bounds__(256, 4) void vq_kernel(
    const float* __restrict__ x2t, const float* __restrict__ eT,
    const float* __restrict__ eew, const float* __restrict__ vvs,
    const float* __restrict__ emb,
    const float* __restrict__ Wa, const float* __restrict__ ba,
    const float* __restrict__ Wv, const float* __restrict__ bv,
    float* __restrict__ out, int rstride)
{
    __shared__ float smem[4224 * 2 + 512];        // 35 KB
    float* xL  = smem;                            // [32][132]
    float* eL  = smem + 4224;                     // [32][132]
    float* eeL = smem + 8448;                     // [512]
    const int tid = threadIdx.x;
    const int tr = tid & 15;
    const int tc = tid >> 4;
    const int brow = blockIdx.x * 128;

    eeL[tid] = eew[tid];
    eeL[tid + 256] = eew[tid + 256];

    float4 vvA = *(const float4*)(vvs + brow + tr * 4);
    float4 vvB = *(const float4*)(vvs + brow + 64 + tr * 4);

    float bestA[4], bestB[4];
    int biA[4], biB[4];
#pragma unroll
    for (int q = 0; q < 4; ++q) {
        bestA[q] = FLT_MAX; bestB[q] = FLT_MAX; biA[q] = 0; biB[q] = 0;
    }

#define FMA8(ri, xv) \
    acc[ri][0] = fmaf(xv, e0.x, acc[ri][0]); acc[ri][1] = fmaf(xv, e0.y, acc[ri][1]); \
    acc[ri][2] = fmaf(xv, e0.z, acc[ri][2]); acc[ri][3] = fmaf(xv, e0.w, acc[ri][3]); \
    acc[ri][4] = fmaf(xv, e1.x, acc[ri][4]); acc[ri][5] = fmaf(xv, e1.y, acc[ri][5]); \
    acc[ri][6] = fmaf(xv, e1.z, acc[ri][6]); acc[ri][7] = fmaf(xv, e1.w, acc[ri][7]);

    for (int cb = 0; cb < 4; ++cb) {
        float acc[8][8];
#pragma unroll
        for (int ri = 0; ri < 8; ++ri)
#pragma unroll
            for (int ci = 0; ci < 8; ++ci) acc[ri][ci] = 0.f;

        for (int kc = 0; kc < 4; ++kc) {
            __syncthreads();                      // prev chunk consumed
#pragma unroll
            for (int u = 0; u < 4; ++u) {
                int idx = tid + 256 * u;          // 0..1023
                int kk = idx >> 5, rq = idx & 31;
                float4 xv = *(const float4*)(x2t + (size_t)(kc * 32 + kk) * rstride + brow + 4 * rq);
                *(float4*)(xL + kk * 132 + 4 * rq) = xv;
                float4 ev = *(const float4*)(eT + (size_t)(kc * 32 + kk) * KCODES + cb * 128 + 4 * rq);
                *(float4*)(eL + kk * 132 + 4 * rq) = ev;
            }
            __syncthreads();
#pragma unroll 2
            for (int k = 0; k < 32; ++k) {        // k ascending: exact dot chain
                float4 xa = *(const float4*)(xL + k * 132 + tr * 4);
                float4 xb = *(const float4*)(xL + k * 132 + 64 + tr * 4);
                float4 e0 = *(const float4*)(eL + k * 132 + tc * 8);
                float4 e1 = *(const float4*)(eL + k * 132 + tc * 8 + 4);
                FMA8(0, xa.x) FMA8(1, xa.y) FMA8(2, xa.z) FMA8(3, xa.w)
                FMA8(4, xb.x) FMA8(5, xb.y) FMA8(6, xb.z) FMA8(7, xb.w)
            }
        }
        const int cbase = cb * 128 + tc * 8;
#pragma unroll
        for (int ci = 0; ci < 8; ++ci) {
            float ec = eeL[cbase + ci];
#pragma unroll
            for (int q = 0; q < 4; ++q) {
                float dd = (vvA_q(q) - 2.f * acc[q][ci]) + ec;
                if (dd < bestA[q]) { bestA[q] = dd; biA[q] = cbase + ci; }
                float dd2 = (vvB_q(q) - 2.f * acc[4 + q][ci]) + ec;
                if (dd2 < bestB[q]) { bestB[q] = dd2; biB[q] = cbase + ci; }
            }
        }
    }
#undef FMA8

    __syncthreads();                              // compute done; reuse smem
    float* redB = smem;                           // [128][17]
    int*   redI = (int*)(smem + 2304);            // [128][17]
#pragma unroll
    for (int q = 0; q < 4; ++q) {
        redB[(tr * 4 + q) * 17 + tc] = bestA[q];
        redI[(tr * 4 + q) * 17 + tc] = biA[q];
        redB[(64 + tr * 4 + q) * 17 + tc] = bestB[q];
        redI[(64 + tr * 4 + q) * 17 + tc] = biB[q];
    }
    __syncthreads();

    if (tid < 128) {
        float bb = redB[tid * 17];
        int bix = redI[tid * 17];
#pragma unroll
        for (int q = 1; q < 16; ++q) {
            float b = redB[tid * 17 + q];
            int i = redI[tid * 17 + q];
            if (b < bb || (b == bb && i < bix)) { bb = b; bix = i; }
        }

        const int row = brow + tid;
        float lg[ADIM];
#pragma unroll
        for (int a = 0; a < ADIM; ++a) lg[a] = ba[a];
        float val = bv[0];

        const float4* q4 = (const float4*)(emb + (size_t)bix * HDIM);
#pragma unroll
        for (int j4 = 0; j4 < HDIM / 4; ++j4) {
            float4 q = q4[j4];
            const int j = 4 * j4;
#pragma unroll
            for (int a = 0; a < ADIM; ++a) {
                float t = lg[a];
                t = fmaf(q.x, Wa[(j + 0) * ADIM + a], t);
                t = fmaf(q.y, Wa[(j + 1) * ADIM + a], t);
                t = fmaf(q.z, Wa[(j + 2) * ADIM + a], t);
                t = fmaf(q.w, Wa[(j + 3) * ADIM + a], t);
                lg[a] = t;
            }
            val = fmaf(q.x, Wv[j + 0], val);
            val = fmaf(q.y, Wv[j + 1], val);
            val = fmaf(q.z, Wv[j + 2], val);
            val = fmaf(q.w, Wv[j + 3], val);
        }

        float m = lg[0];
#pragma unroll
        for (int a = 1; a < ADIM; ++a) m = fmaxf(m, lg[a]);
        float p[ADIM];
        float s = 0.f;
#pragma unroll
        for (int a = 0; a < ADIM; ++a) { p[a] = __expf(lg[a] - m); s += p[a]; }
        const float inv = 1.f / s;

        float4* outp = (float4*)(out + (size_t)row * ADIM);
        outp[0] = make_float4(p[0] * inv, p[1] * inv, p[2] * inv, p[3] * inv);
        outp[1] = make_float4(p[4] * inv, p[5] * inv, p[6] * inv, p[7] * inv);
        out[(size_t)NROWS * ADIM + row] = val;
    }
}

// ===========================================================================
// Fallback (ws too small; never expected): round-4 global-feed path.
// ===========================================================================
#define R16(M) M(0) M(1) M(2) M(3) M(4) M(5) M(6) M(7) \
               M(8) M(9) M(10) M(11) M(12) M(13) M(14) M(15)
#define R32(M) R16(M) M(16) M(17) M(18) M(19) M(20) M(21) M(22) M(23) \
               M(24) M(25) M(26) M(27) M(28) M(29) M(30) M(31)
#define PIN4(v) asm volatile("" : "+v"(v.x), "+v"(v.y), "+v"(v.z), "+v"(v.w));

__global__ __launch_bounds__(256, 2) void fused_global_kernel(
    const float* __restrict__ in,
    const float* __restrict__ W1, const float* __restrict__ b1,
    const float* __restrict__ Wh, const float* __restrict__ bh,
    const float* __restrict__ emb,
    const float* __restrict__ Wa, const float* __restrict__ ba,
    const float* __restrict__ Wv, const float* __restrict__ bv,
    float* __restrict__ out)
{
    __shared__ float ee_s[KCODES];
    const int tid = threadIdx.x;
    const int row = blockIdx.x * 256 + tid;

#pragma unroll
    for (int kk = 0; kk < 2; ++kk) {
        int k = tid + 256 * kk;
        const float* e = emb + k * HDIM;
        float a0 = 0.f, a1 = 0.f, a2 = 0.f, a3 = 0.f;
#pragma unroll
        for (int j = 0; j < HDIM; j += 4) {
            a0 = fmaf(e[j + 0], e[j + 0], a0);
            a1 = fmaf(e[j + 1], e[j + 1], a1);
            a2 = fmaf(e[j + 2], e[j + 2], a2);
            a3 = fmaf(e[j + 3], e[j + 3], a3);
        }
        ee_s[k] = (a0 + a1) + (a2 + a3);
    }
    __syncthreads();

    const float4* inr4 = (const float4*)(in + (size_t)row * SDIM);
#define DECLI(n) float4 i##n = inr4[n]; PIN4(i##n)
    R16(DECLI)
#define DECLX(m) float4 x##m = make_float4(bh[4*(m)+0], bh[4*(m)+1], bh[4*(m)+2], bh[4*(m)+3]);
    R32(DECLX)

#define L1N(n) xt = fmaf(i##n.x, wc[(4*(n)+0)*HDIM], xt); xt = fmaf(i##n.y, wc[(4*(n)+1)*HDIM], xt); \
               xt = fmaf(i##n.z, wc[(4*(n)+2)*HDIM], xt); xt = fmaf(i##n.w, wc[(4*(n)+3)*HDIM], xt);
#define L2(m)  x##m.x = fmaf(xt, whr[4*(m)+0], x##m.x); x##m.y = fmaf(xt, whr[4*(m)+1], x##m.y); \
               x##m.z = fmaf(xt, whr[4*(m)+2], x##m.z); x##m.w = fmaf(xt, whr[4*(m)+3], x##m.w);
    for (int t = 0; t < HDIM; ++t) {
        float xt = b1[t];
        const float* wc = W1 + t;
        R16(L1N)
        xt = fmaxf(xt, 0.f);
        const float* whr = Wh + t * HDIM;
        R32(L2)
    }
#define RELUX(m) x##m.x = fmaxf(x##m.x, 0.f); x##m.y = fmaxf(x##m.y, 0.f); \
                 x##m.z = fmaxf(x##m.z, 0.f); x##m.w = fmaxf(x##m.w, 0.f); PIN4(x##m)
    R32(RELUX)

    float v0 = 0.f, v1 = 0.f, v2 = 0.f, v3 = 0.f;
#define VV(m) v0 = fmaf(x##m.x, x##m.x, v0); v1 = fmaf(x##m.y, x##m.y, v1); \
              v2 = fmaf(x##m.z, x##m.z, v2); v3 = fmaf(x##m.w, x##m.w, v3);
    R32(VV)
    const float vv = (v0 + v1) + (v2 + v3);

    float best = FLT_MAX;
    int bi = 0;
#define SC(m) \
    d0 = fmaf(x##m.x, eb[0*HDIM+4*(m)+0], d0); d0 = fmaf(x##m.y, eb[0*HDIM+4*(m)+1], d0); \
    d0 = fmaf(x##m.z, eb[0*HDIM+4*(m)+2], d0); d0 = fmaf(x##m.w, eb[0*HDIM+4*(m)+3], d0); \
    d1 = fmaf(x##m.x, eb[1*HDIM+4*(m)+0], d1); d1 = fmaf(x##m.y, eb[1*HDIM+4*(m)+1], d1); \
    d1 = fmaf(x##m.z, eb[1*HDIM+4*(m)+2], d1); d1 = fmaf(x##m.w, eb[1*HDIM+4*(m)+3], d1); \
    d2 = fmaf(x##m.x, eb[2*HDIM+4*(m)+0], d2); d2 = fmaf(x##m.y, eb[2*HDIM+4*(m)+1], d2); \
    d2 = fmaf(x##m.z, eb[2*HDIM+4*(m)+2], d2); d2 = fmaf(x##m.w, eb[2*HDIM+4*(m)+3], d2); \
    d3 = fmaf(x##m.x, eb[3*HDIM+4*(m)+0], d3); d3 = fmaf(x##m.y, eb[3*HDIM+4*(m)+1], d3); \
    d3 = fmaf(x##m.z, eb[3*HDIM+4*(m)+2], d3); d3 = fmaf(x##m.w, eb[3*HDIM+4*(m)+3], d3); \
    d4 = fmaf(x##m.x, eb[4*HDIM+4*(m)+0], d4); d4 = fmaf(x##m.y, eb[4*HDIM+4*(m)+1], d4); \
    d4 = fmaf(x##m.z, eb[4*HDIM+4*(m)+2], d4); d4 = fmaf(x##m.w, eb[4*HDIM+4*(m)+3], d4); \
    d5 = fmaf(x##m.x, eb[5*HDIM+4*(m)+0], d5); d5 = fmaf(x##m.y, eb[5*HDIM+4*(m)+1], d5); \
    d5 = fmaf(x##m.z, eb[5*HDIM+4*(m)+2], d5); d5 = fmaf(x##m.w, eb[5*HDIM+4*(m)+3], d5); \
    d6 = fmaf(x##m.x, eb[6*HDIM+4*(m)+0], d6); d6 = fmaf(x##m.y, eb[6*HDIM+4*(m)+1], d6); \
    d6 = fmaf(x##m.z, eb[6*HDIM+4*(m)+2], d6); d6 = fmaf(x##m.w, eb[6*HDIM+4*(m)+3], d6); \
    d7 = fmaf(x##m.x, eb[7*HDIM+4*(m)+0], d7); d7 = fmaf(x##m.y, eb[7*HDIM+4*(m)+1], d7); \
    d7 = fmaf(x##m.z, eb[7*HDIM+4*(m)+2], d7); d7 = fmaf(x##m.w, eb[7*HDIM+4*(m)+3], d7);
    for (int k0 = 0; k0 < KCODES; k0 += 8) {
        const float* eb = emb + (size_t)k0 * HDIM;
        float d0 = 0.f, d1 = 0.f, d2 = 0.f, d3 = 0.f;
        float d4 = 0.f, d5 = 0.f, d6 = 0.f, d7 = 0.f;
        R32(SC)
        float dd;
        dd = (vv - 2.f * d0) + ee_s[k0 + 0]; if (dd < best) { best = dd; bi = k0 + 0; }
        dd = (vv - 2.f * d1) + ee_s[k0 + 1]; if (dd < best) { best = dd; bi = k0 + 1; }
        dd = (vv - 2.f * d2) + ee_s[k0 + 2]; if (dd < best) { best = dd; bi = k0 + 2; }
        dd = (vv - 2.f * d3) + ee_s[k0 + 3]; if (dd < best) { best = dd; bi = k0 + 3; }
        dd = (vv - 2.f * d4) + ee_s[k0 + 4]; if (dd < best) { best = dd; bi = k0 + 4; }
        dd = (vv - 2.f * d5) + ee_s[k0 + 5]; if (dd < best) { best = dd; bi = k0 + 5; }
        dd = (vv - 2.f * d6) + ee_s[k0 + 6]; if (dd < best) { best = dd; bi = k0 + 6; }
        dd = (vv - 2.f * d7) + ee_s[k0 + 7]; if (dd < best) { best = dd; bi = k0 + 7; }
    }

    float lg[ADIM];
#pragma unroll
    for (int a = 0; a < ADIM; ++a) lg[a] = ba[a];
    float val = bv[0];
    const float4* q4 = (const float4*)(emb + (size_t)bi * HDIM);
#pragma unroll
    for (int j4 = 0; j4 < HDIM / 4; ++j4) {
        float4 q = q4[j4];
        const int j = 4 * j4;
#pragma unroll
        for (int a = 0; a < ADIM; ++a) {
            float t = lg[a];
            t = fmaf(q.x, Wa[(j + 0) * ADIM + a], t);
            t = fmaf(q.y, Wa[(j + 1) * ADIM + a], t);
            t = fmaf(q.z, Wa[(j + 2) * ADIM + a], t);
            t = fmaf(q.w, Wa[(j + 3) * ADIM + a], t);
            lg[a] = t;
        }
        val = fmaf(q.x, Wv[j + 0], val);
        val = fmaf(q.y, Wv[j + 1], val);
        val = fmaf(q.z, Wv[j + 2], val);
        val = fmaf(q.w, Wv[j + 3], val);
    }
    float m = lg[0];
#pragma unroll
    for (int a = 1; a < ADIM; ++a) m = fmaxf(m, lg[a]);
    float p[ADIM];
    float s = 0.f;
#pragma unroll
    for (int a = 0; a < ADIM; ++a) { p[a] = __expf(lg[a] - m); s += p[a]; }
    const float inv = 1.f / s;
    float4* outp = (float4*)(out + (size_t)row * ADIM);
    outp[0] = make_float4(p[0] * inv, p[1] * inv, p[2] * inv, p[3] * inv);
    outp[1] = make_float4(p[4] * inv, p[5] * inv, p[6] * inv, p[7] * inv);
    out[(size_t)NROWS * ADIM + row] = val;
}

// ===========================================================================
extern "C" void kernel_launch(void* const* d_in, const int* in_sizes, int n_in,
                              void* d_out, int out_size, void* d_ws, size_t ws_size,
                              hipStream_t stream) {
    const float* in  = (const float*)d_in[0];
    const float* W1  = (const float*)d_in[1];
    const float* b1  = (const float*)d_in[2];
    const float* Wh  = (const float*)d_in[3];
    const float* bh  = (const float*)d_in[4];
    const float* emb = (const float*)d_in[5];
    const float* Wa  = (const float*)d_in[6];
    const float* ba  = (const float*)d_in[7];
    const float* Wv  = (const float*)d_in[8];
    const float* bv  = (const float*)d_in[9];
    float* out = (float*)d_out;

    const size_t x2_f = (size_t)NROWS * HDIM;             // 64 MB
    const size_t eT_f = (size_t)KCODES * HDIM;            // 256 KB
    const size_t ee_f = KCODES;                           // 2 KB
    const size_t vv_f = NROWS;                            // 512 KB
    const size_t need = (x2_f + eT_f + ee_f + vv_f) * sizeof(float);

    if (ws_size >= need) {
        float* x2t = (float*)d_ws;
        float* eTp = x2t + x2_f;
        float* eew = eTp + eT_f;
        float* vvs = eew + ee_f;
        prep_e_kernel<<<64, 256, 0, stream>>>(emb, eTp);
        ee_kernel<<<2, 256, 0, stream>>>(emb, eew);
        mlp_kernel<<<NROWS / 128, 256, 0, stream>>>(in, W1, b1, Wh, bh, x2t, vvs, NROWS);
        vq_kernel<<<NROWS / 128, 256, 0, stream>>>(x2t, eTp, eew, vvs, emb,
                                                   Wa, ba, Wv, bv, out, NROWS);
    } else {
        fused_global_kernel<<<NROWS / 256, 256, 0, stream>>>(in, W1, b1, Wh, bh, emb,
                                                             Wa, ba, Wv, bv, out);
    }
}